// Round 2
// baseline (2527.491 us; speedup 1.0000x reference)
//
#include <hip/hip_runtime.h>

typedef unsigned short ushort_t;
typedef short short8 __attribute__((ext_vector_type(8)));
typedef unsigned short ushort8 __attribute__((ext_vector_type(8)));
typedef float floatx4 __attribute__((ext_vector_type(4)));

#define NB 256   // batch
#define TT 128   // time steps
#define II 512   // input dim
#define HH 512   // hidden dim
#define NTH (NB * TT * HH)   // 16,777,216 elements per output tensor

__device__ __forceinline__ float bf2f(ushort_t u) {
    union { unsigned int i; float f; } v;
    v.i = ((unsigned int)u) << 16;
    return v.f;
}
__device__ __forceinline__ ushort_t f2bf(float f) {
    union { float f; unsigned int i; } v;
    v.f = f;
    unsigned int u = v.i;
    u += 0x7fffu + ((u >> 16) & 1u);   // round-to-nearest-even
    return (ushort_t)(u >> 16);
}
__device__ __forceinline__ float sigmoid_(float x) { return 1.f / (1.f + __expf(-x)); }
__device__ __forceinline__ float mish_(float v) {
    float sp = (v > 20.f) ? v : log1pf(__expf(v));
    return v * tanhf(sp);
}

// ---------------------------------------------------------------------------
// fp32 -> bf16 bulk convert, 8 elems/thread. n8 = n/8 (n multiple of 8).
// ---------------------------------------------------------------------------
__global__ __launch_bounds__(256) void cvt_bf16_kernel(
    const float* __restrict__ src, ushort_t* __restrict__ dst, int n8)
{
    int i = blockIdx.x * 256 + threadIdx.x;
    if (i >= n8) return;
    const float4* s = (const float4*)src;
    float4 a = s[i * 2];
    float4 b = s[i * 2 + 1];
    ushort8 v;
    v[0] = f2bf(a.x); v[1] = f2bf(a.y); v[2] = f2bf(a.z); v[3] = f2bf(a.w);
    v[4] = f2bf(b.x); v[5] = f2bf(b.y); v[6] = f2bf(b.z); v[7] = f2bf(b.w);
    ((ushort8*)dst)[i] = v;
}

// ---------------------------------------------------------------------------
// Init: h0 = bf16(hx[:,0,:]), c0 = cx[:,0,:] fp32, b_comb = b_ih + b_hh fp32.
// ---------------------------------------------------------------------------
__global__ __launch_bounds__(256) void init_kernel(
    const float* __restrict__ hx, const float* __restrict__ cx,
    const float* __restrict__ b_ih, const float* __restrict__ b_hh,
    ushort_t* __restrict__ hb0, float* __restrict__ c_state,
    float* __restrict__ b_comb)
{
    int idx = blockIdx.x * 256 + threadIdx.x;   // over NB*HH = 131072
    int m = idx >> 9;                            // /512
    int h = idx & 511;
    size_t src = (size_t)m * TT * HH + h;        // t = 0 slice
    hb0[idx] = f2bf(hx[src]);
    c_state[idx] = cx[src];
    if (idx < 4 * HH) b_comb[idx] = b_ih[idx] + b_hh[idx];
}

// ---------------------------------------------------------------------------
// One LSTM step. Grid: 512 blocks (16 m-tiles x 32 h-tiles), 256 thr = 4 waves.
// Wave g computes gate g's 16x16 preactivation tile via MFMA over K=1024
// ([x_t ; h_eff] x [W_ih ; W_hh]^T), all operands bf16 (pre-converted).
// Gates combined via LDS; cell update fp32. reset zeroes h rows / c.
// ---------------------------------------------------------------------------
__global__ __launch_bounds__(256) void step_kernel(
    const ushort_t* __restrict__ xb,       // (NB,TT,II) bf16 (converted)
    const int* __restrict__ is_init,       // (NB,TT) int32
    const ushort_t* __restrict__ wihb,     // (2048,512) bf16
    const ushort_t* __restrict__ whhb,     // (2048,512) bf16
    const float* __restrict__ b_comb,      // (2048) fp32
    const ushort_t* __restrict__ hb_cur,   // (NB,HH) bf16
    ushort_t* __restrict__ hb_nxt,         // (NB,HH) bf16
    float* __restrict__ c_state,           // (NB,HH) fp32
    ushort_t* __restrict__ hs_out,         // (NB,TT,HH) bf16 staging
    int t)
{
    __shared__ float gbuf[4][16][16];

    const int tid  = threadIdx.x;
    const int gate = tid >> 6;        // wave index == gate index (i,f,g,o)
    const int lane = tid & 63;
    const int quad = lane >> 4;
    const int l15  = lane & 15;
    const int bm = blockIdx.x >> 5;   // 0..15
    const int bh = blockIdx.x & 31;   // 0..31
    const int m0 = bm * 16;
    const int h0 = bh * 16;

    const int m_a = m0 + l15;               // A row
    const int n   = gate * HH + h0 + l15;   // B row (gate column in [0,2048))

    const short8* xrow = (const short8*)(xb + ((size_t)(m_a * TT + t)) * II);
    const short8* hrow = (const short8*)(hb_cur + (size_t)m_a * HH);
    const short8* wih  = (const short8*)(wihb + (size_t)n * II);
    const short8* whh  = (const short8*)(whhb + (size_t)n * HH);

    const int init_a = is_init[m_a * TT + t];   // row mask for h (A rows)

    floatx4 acc = {0.f, 0.f, 0.f, 0.f};
    short8 z8 = {0, 0, 0, 0, 0, 0, 0, 0};

    // K = 0..511 : x_t @ W_ih^T   (no reset mask on x)
#pragma unroll
    for (int kk = 0; kk < 16; ++kk) {
        int c8 = kk * 4 + quad;           // element offset /8 = kk*32 + quad*8
        short8 a = xrow[c8];
        short8 b = wih[c8];
        acc = __builtin_amdgcn_mfma_f32_16x16x32_bf16(a, b, acc, 0, 0, 0);
    }
    // K = 512..1023 : h_eff @ W_hh^T  (h row zeroed when is_init==1)
#pragma unroll
    for (int kk = 0; kk < 16; ++kk) {
        int c8 = kk * 4 + quad;
        short8 a = init_a ? z8 : hrow[c8];
        short8 b = whh[c8];
        acc = __builtin_amdgcn_mfma_f32_16x16x32_bf16(a, b, acc, 0, 0, 0);
    }

    // D layout: row = quad*4 + r, col = l15
#pragma unroll
    for (int r = 0; r < 4; ++r)
        gbuf[gate][quad * 4 + r][l15] = acc[r];
    __syncthreads();

    // Pointwise cell update: thread -> one (m,h)
    const int ml = tid >> 4;
    const int hl = tid & 15;
    const int m = m0 + ml;
    const int h = h0 + hl;

    float iv = gbuf[0][ml][hl] + b_comb[0 * HH + h];
    float fv = gbuf[1][ml][hl] + b_comb[1 * HH + h];
    float gv = gbuf[2][ml][hl] + b_comb[2 * HH + h];
    float ov = gbuf[3][ml][hl] + b_comb[3 * HH + h];

    float cp = c_state[m * HH + h];
    if (is_init[m * TT + t]) cp = 0.f;    // c_eff = c * reset

    float cn = sigmoid_(fv) * cp + sigmoid_(iv) * tanhf(gv);
    float hn = sigmoid_(ov) * tanhf(cn);

    c_state[m * HH + h] = cn;
    ushort_t hb = f2bf(hn);
    hb_nxt[m * HH + h] = hb;
    hs_out[(size_t)m * (TT * HH) + (size_t)t * HH + h] = hb;
}

// ---------------------------------------------------------------------------
// Output projection: out0 = mish(hs @ W_out^T + b_out), fp32 out.
// Block = 64x64 tile (4 waves, 2x2 of 16x16x(4-reg) per wave). Grid 4096.
// ---------------------------------------------------------------------------
__global__ __launch_bounds__(256) void outproj_kernel(
    const ushort_t* __restrict__ hs,     // (NB*TT, HH) bf16 staging
    const ushort_t* __restrict__ W_outb, // (HH, HH) bf16
    const float* __restrict__ b_out,     // (HH) fp32
    float* __restrict__ out0)            // (NB*TT, HH) fp32
{
    const int tid  = threadIdx.x;
    const int wv   = tid >> 6;
    const int lane = tid & 63;
    const int quad = lane >> 4;
    const int l15  = lane & 15;

    const int bx = blockIdx.x;
    const int bm = bx >> 3;              // 0..511
    const int bn = bx & 7;               // 0..7
    const int m0 = bm * 64 + (wv >> 1) * 32;
    const int n0 = bn * 64 + (wv & 1) * 32;

    const short8* arow0 = (const short8*)(hs + (size_t)(m0 + l15) * HH);
    const short8* arow1 = (const short8*)(hs + (size_t)(m0 + 16 + l15) * HH);
    const short8* brow0 = (const short8*)(W_outb + (size_t)(n0 + l15) * HH);
    const short8* brow1 = (const short8*)(W_outb + (size_t)(n0 + 16 + l15) * HH);

    floatx4 acc00 = {0.f,0.f,0.f,0.f}, acc01 = {0.f,0.f,0.f,0.f};
    floatx4 acc10 = {0.f,0.f,0.f,0.f}, acc11 = {0.f,0.f,0.f,0.f};

#pragma unroll 4
    for (int kk = 0; kk < 16; ++kk) {
        int c8 = kk * 4 + quad;
        short8 a0 = arow0[c8];
        short8 a1 = arow1[c8];
        short8 b0 = brow0[c8];
        short8 b1 = brow1[c8];
        acc00 = __builtin_amdgcn_mfma_f32_16x16x32_bf16(a0, b0, acc00, 0, 0, 0);
        acc01 = __builtin_amdgcn_mfma_f32_16x16x32_bf16(a0, b1, acc01, 0, 0, 0);
        acc10 = __builtin_amdgcn_mfma_f32_16x16x32_bf16(a1, b0, acc10, 0, 0, 0);
        acc11 = __builtin_amdgcn_mfma_f32_16x16x32_bf16(a1, b1, acc11, 0, 0, 0);
    }

    float bo0 = b_out[n0 + l15];
    float bo1 = b_out[n0 + 16 + l15];

#pragma unroll
    for (int r = 0; r < 4; ++r) {
        size_t row0 = (size_t)(m0 + quad * 4 + r) * HH;
        size_t row1 = (size_t)(m0 + 16 + quad * 4 + r) * HH;
        out0[row0 + n0 + l15]      = mish_(acc00[r] + bo0);
        out0[row0 + n0 + 16 + l15] = mish_(acc01[r] + bo1);
        out0[row1 + n0 + l15]      = mish_(acc10[r] + bo0);
        out0[row1 + n0 + 16 + l15] = mish_(acc11[r] + bo1);
    }
}

// ---------------------------------------------------------------------------
// Broadcast h_T / c_T to (NB,TT,HH) fp32. 8 elems per thread.
// ---------------------------------------------------------------------------
__global__ __launch_bounds__(256) void broadcast_kernel(
    const ushort_t* __restrict__ hT,   // (NB,HH) bf16
    const float* __restrict__ cT,      // (NB,HH) fp32
    float* __restrict__ h_rep, float* __restrict__ c_rep)
{
    size_t idx  = (size_t)blockIdx.x * 256 + threadIdx.x;   // 0 .. NTH/8-1
    size_t flat = idx * 8;
    int m = (int)(flat >> 16);        // / (TT*HH)
    int h = (int)(flat & 511);

    const ushort_t* hp = hT + (size_t)m * HH + h;
    const float*    cp = cT + (size_t)m * HH + h;

    float4 h0v, h1v, c0v, c1v;
    h0v.x = bf2f(hp[0]); h0v.y = bf2f(hp[1]); h0v.z = bf2f(hp[2]); h0v.w = bf2f(hp[3]);
    h1v.x = bf2f(hp[4]); h1v.y = bf2f(hp[5]); h1v.z = bf2f(hp[6]); h1v.w = bf2f(hp[7]);
    c0v.x = cp[0]; c0v.y = cp[1]; c0v.z = cp[2]; c0v.w = cp[3];
    c1v.x = cp[4]; c1v.y = cp[5]; c1v.z = cp[6]; c1v.w = cp[7];

    *(float4*)(h_rep + flat)     = h0v;
    *(float4*)(h_rep + flat + 4) = h1v;
    *(float4*)(c_rep + flat)     = c0v;
    *(float4*)(c_rep + flat + 4) = c1v;
}

// ---------------------------------------------------------------------------
extern "C" void kernel_launch(void* const* d_in, const int* in_sizes, int n_in,
                              void* d_out, int out_size, void* d_ws, size_t ws_size,
                              hipStream_t stream) {
    const float* x      = (const float*)d_in[0];
    const int*   isini  = (const int*)d_in[1];
    const float* hx     = (const float*)d_in[2];
    const float* cx     = (const float*)d_in[3];
    const float* W_ih   = (const float*)d_in[4];
    const float* W_hh   = (const float*)d_in[5];
    const float* b_ih   = (const float*)d_in[6];
    const float* b_hh   = (const float*)d_in[7];
    const float* W_out  = (const float*)d_in[8];
    const float* b_out  = (const float*)d_in[9];

    float* out   = (float*)d_out;
    float* h_rep = out + (size_t)NTH;
    float* c_rep = out + (size_t)2 * NTH;

    // bf16 staging inside d_out's not-yet-final regions:
    //  - W_ih/W_hh bf16 at head of out0 (dead once steps finish, before outproj writes)
    //  - hs bf16 in h_rep region (dead after outproj, before broadcast writes)
    //  - x  bf16 in c_rep region (dead after steps, before broadcast writes)
    ushort_t* wihb = (ushort_t*)out;                       // 2 MiB
    ushort_t* whhb = wihb + (size_t)4 * HH * II;           // 2 MiB
    ushort_t* hsb  = (ushort_t*)h_rep;                     // 32 MiB used
    ushort_t* xb   = (ushort_t*)c_rep;                     // 32 MiB used

    // workspace: small state only (~1.5 MiB)
    char* wsb = (char*)d_ws;
    ushort_t* hb0     = (ushort_t*)wsb;                               // 256 KiB
    ushort_t* hb1     = (ushort_t*)(wsb + (size_t)NB * HH * 2);       // 256 KiB
    float*    c_state = (float*)(wsb + (size_t)2 * NB * HH * 2);      // 512 KiB
    float*    b_comb  = (float*)(wsb + (size_t)2 * NB * HH * 2
                                     + (size_t)NB * HH * 4);          // 8 KiB
    ushort_t* woutb   = (ushort_t*)(wsb + (size_t)2 * NB * HH * 2
                                        + (size_t)NB * HH * 4 + 4 * HH * 4); // 512 KiB

    // --- prep: fp32 -> bf16 conversions ---
    cvt_bf16_kernel<<<(NTH / 8 + 255) / 256, 256, 0, stream>>>(x, xb, NTH / 8);
    cvt_bf16_kernel<<<(4 * HH * II / 8 + 255) / 256, 256, 0, stream>>>(W_ih, wihb, 4 * HH * II / 8);
    cvt_bf16_kernel<<<(4 * HH * HH / 8 + 255) / 256, 256, 0, stream>>>(W_hh, whhb, 4 * HH * HH / 8);
    cvt_bf16_kernel<<<(HH * HH / 8 + 255) / 256, 256, 0, stream>>>(W_out, woutb, HH * HH / 8);
    init_kernel<<<NB * HH / 256, 256, 0, stream>>>(hx, cx, b_ih, b_hh, hb0, c_state, b_comb);

    // --- recurrence ---
    for (int t = 0; t < TT; ++t) {
        ushort_t* cur = (t & 1) ? hb1 : hb0;
        ushort_t* nxt = (t & 1) ? hb0 : hb1;
        step_kernel<<<512, 256, 0, stream>>>(xb, isini, wihb, whhb, b_comb,
                                             cur, nxt, c_state, hsb, t);
    }

    // --- epilogue ---
    outproj_kernel<<<4096, 256, 0, stream>>>(hsb, woutb, b_out, out);

    // final h lives in hb0 after t=127 (odd t writes into hb0)
    broadcast_kernel<<<NTH / 8 / 256, 256, 0, stream>>>(hb0, c_state, h_rep, c_rep);
}

// Round 4
// 2377.306 us; speedup vs baseline: 1.0632x; 1.0632x over previous
//
#include <hip/hip_runtime.h>

typedef unsigned short ushort_t;
typedef short short8 __attribute__((ext_vector_type(8)));
typedef unsigned short ushort8 __attribute__((ext_vector_type(8)));
typedef float floatx4 __attribute__((ext_vector_type(4)));

#define NB 256   // batch
#define TT 128   // time steps
#define II 512   // input dim
#define HH 512   // hidden dim
#define NTH (NB * TT * HH)   // 16,777,216 elements per output tensor
#define RBLK 256             // recurrence grid blocks (1 per CU)

__device__ __forceinline__ float bf2f(ushort_t u) {
    union { unsigned int i; float f; } v;
    v.i = ((unsigned int)u) << 16;
    return v.f;
}
__device__ __forceinline__ ushort_t f2bf(float f) {
    union { float f; unsigned int i; } v;
    v.f = f;
    unsigned int u = v.i;
    u += 0x7fffu + ((u >> 16) & 1u);   // round-to-nearest-even
    return (ushort_t)(u >> 16);
}
__device__ __forceinline__ float sigmoid_(float x) { return 1.f / (1.f + __expf(-x)); }
__device__ __forceinline__ float tanh_fast(float x) {
    // 1 - 2/(e^{2x}+1); exp overflow -> inf -> 1 (correct saturation)
    return 1.f - 2.f / (__expf(2.f * x) + 1.f);
}
__device__ __forceinline__ float mish_fast(float v) {
    // v * tanh(softplus(v)) == v * t/(t+2), t = e*(e+2), e = exp(v) (exact)
    float e = __expf(fminf(v, 20.f));
    float t = e * (e + 2.f);
    return v * t / (t + 2.f);
}

// ---------------------------------------------------------------------------
// Manual grid barrier (sense-reversal), device-scope atomics + agent fences.
// All RBLK blocks are co-resident (1 block/CU). Vars zeroed by init_kernel.
// ---------------------------------------------------------------------------
__device__ __forceinline__ void grid_barrier(unsigned* cnt, unsigned* sns,
                                             unsigned& my_sense)
{
    __syncthreads();                 // all waves' stores drained (vmcnt 0)
    if (threadIdx.x == 0) {
        unsigned s = my_sense ^ 1u;
        __threadfence();             // release: writeback for cross-XCD
        unsigned prev = __hip_atomic_fetch_add(cnt, 1u, __ATOMIC_RELAXED,
                                               __HIP_MEMORY_SCOPE_AGENT);
        if (prev == RBLK - 1u) {
            __hip_atomic_store(cnt, 0u, __ATOMIC_RELAXED, __HIP_MEMORY_SCOPE_AGENT);
            __hip_atomic_store(sns, s, __ATOMIC_RELEASE, __HIP_MEMORY_SCOPE_AGENT);
        } else {
            while (__hip_atomic_load(sns, __ATOMIC_RELAXED,
                                     __HIP_MEMORY_SCOPE_AGENT) != s)
                __builtin_amdgcn_s_sleep(2);
        }
        __threadfence();             // acquire: invalidate L1/L2 for fresh reads
        my_sense = s;
    }
    __syncthreads();
}

// ---------------------------------------------------------------------------
// fp32 -> bf16 bulk convert, 8 elems/thread.
// ---------------------------------------------------------------------------
__global__ __launch_bounds__(256) void cvt_bf16_kernel(
    const float* __restrict__ src, ushort_t* __restrict__ dst, int n8)
{
    int i = blockIdx.x * 256 + threadIdx.x;
    if (i >= n8) return;
    const float4* s = (const float4*)src;
    float4 a = s[i * 2];
    float4 b = s[i * 2 + 1];
    ushort8 v;
    v[0] = f2bf(a.x); v[1] = f2bf(a.y); v[2] = f2bf(a.z); v[3] = f2bf(a.w);
    v[4] = f2bf(b.x); v[5] = f2bf(b.y); v[6] = f2bf(b.z); v[7] = f2bf(b.w);
    ((ushort8*)dst)[i] = v;
}

// ---------------------------------------------------------------------------
// Init: hp0 = bf16(hx[:,0,:]); b_comb = b_ih + b_hh; zero barrier vars.
// ---------------------------------------------------------------------------
__global__ __launch_bounds__(256) void init_kernel(
    const float* __restrict__ hx,
    const float* __restrict__ b_ih, const float* __restrict__ b_hh,
    ushort_t* __restrict__ hp0, float* __restrict__ b_comb,
    unsigned* __restrict__ bar_cnt, unsigned* __restrict__ bar_sns)
{
    int idx = blockIdx.x * 256 + threadIdx.x;   // over NB*HH
    int m = idx >> 9;
    int h = idx & 511;
    hp0[idx] = f2bf(hx[(size_t)m * TT * HH + h]);
    if (idx < 4 * HH) b_comb[idx] = b_ih[idx] + b_hh[idx];
    if (idx == 0) { *bar_cnt = 0u; *bar_sns = 0u; }
}

// ---------------------------------------------------------------------------
// LDS-tiled bf16 GEMM: C[M,N] = A[M,512] * B[N,512]^T + bias, 128x128 tiles.
// bm = bx & 255 (A-tile), bn = bx >> 8 -> bn-siblings stride-256 = same XCD,
// so an A-tile is fetched from HBM once per XCD (kills R2's 4x over-fetch).
// MODE 0: scatter-store bf16 Gx[t][n][col] (A-row = n*128+t), bias=b_comb.
// MODE 1: out fp32 = mish(acc + bias) straight store.
// ---------------------------------------------------------------------------
template<int MODE>
__global__ __launch_bounds__(256, 2) void gemm_kernel(
    const ushort_t* __restrict__ A, const ushort_t* __restrict__ B,
    const float* __restrict__ bias,
    ushort_t* __restrict__ gx_lo, ushort_t* __restrict__ gx_hi,
    float* __restrict__ outp)
{
    __shared__ ushort_t As[128 * 32];
    __shared__ ushort_t Bs[128 * 32];
    const int tid  = threadIdx.x;
    const int wv   = tid >> 6;
    const int lane = tid & 63;
    const int q    = lane >> 4;
    const int l15  = lane & 15;
    const int bm   = blockIdx.x & 255;
    const int bn   = blockIdx.x >> 8;
    const int mh   = (wv >> 1) * 64;
    const int nh   = (wv & 1) * 64;

    const ushort_t* Ab = A + (size_t)bm * 128 * 512;
    const ushort_t* Bb = B + (size_t)bn * 128 * 512;

    const int r0 = tid >> 2;        // 0..63
    const int r1 = r0 + 64;         // 64..127
    const int k8 = (tid & 3) * 8;

    floatx4 acc[4][4];
#pragma unroll
    for (int i = 0; i < 4; ++i)
#pragma unroll
        for (int j = 0; j < 4; ++j) acc[i][j] = (floatx4){0.f, 0.f, 0.f, 0.f};

    for (int kt = 0; kt < 16; ++kt) {
        const int kc = kt * 32 + k8;
        short8 a0 = *(const short8*)(Ab + (size_t)r0 * 512 + kc);
        short8 a1 = *(const short8*)(Ab + (size_t)r1 * 512 + kc);
        short8 b0 = *(const short8*)(Bb + (size_t)r0 * 512 + kc);
        short8 b1 = *(const short8*)(Bb + (size_t)r1 * 512 + kc);
        __syncthreads();
        *(short8*)&As[r0 * 32 + k8] = a0;
        *(short8*)&As[r1 * 32 + k8] = a1;
        *(short8*)&Bs[r0 * 32 + k8] = b0;
        *(short8*)&Bs[r1 * 32 + k8] = b1;
        __syncthreads();
        short8 af[4], bfr[4];
#pragma unroll
        for (int s = 0; s < 4; ++s) af[s]  = *(const short8*)&As[(mh + s * 16 + l15) * 32 + q * 8];
#pragma unroll
        for (int s = 0; s < 4; ++s) bfr[s] = *(const short8*)&Bs[(nh + s * 16 + l15) * 32 + q * 8];
#pragma unroll
        for (int i = 0; i < 4; ++i)
#pragma unroll
            for (int j = 0; j < 4; ++j)
                acc[i][j] = __builtin_amdgcn_mfma_f32_16x16x32_bf16(af[i], bfr[j], acc[i][j], 0, 0, 0);
    }

    float bv[4];
#pragma unroll
    for (int j = 0; j < 4; ++j) bv[j] = bias[bn * 128 + nh + j * 16 + l15];

#pragma unroll
    for (int i = 0; i < 4; ++i) {
        const int rowb = bm * 128 + mh + i * 16 + q * 4;
#pragma unroll
        for (int r = 0; r < 4; ++r) {
            const int row = rowb + r;
            if (MODE == 0) {
                const int n = row >> 7, t = row & 127;
                ushort_t* base = (t < 64) ? (gx_lo + ((size_t)t * NB + n) * 2048)
                                          : (gx_hi + ((size_t)(t - 64) * NB + n) * 2048);
#pragma unroll
                for (int j = 0; j < 4; ++j)
                    base[bn * 128 + nh + j * 16 + l15] = f2bf(acc[i][j][r] + bv[j]);
            } else {
                float* ob = outp + (size_t)row * 512;
#pragma unroll
                for (int j = 0; j < 4; ++j)
                    ob[bn * 128 + nh + j * 16 + l15] = mish_fast(acc[i][j][r] + bv[j]);
            }
        }
    }
}

// ---------------------------------------------------------------------------
// Persistent recurrence, NORMAL launch + manual grid barrier. 256 blocks
// (1/CU) x 256 threads. Block (bm,bh) owns batch rows bm*16..+15, hidden
// cols bh*32..+31. W_hh fragments (4 gates x 32 cols x K=512) live in 128
// VGPRs for all 128 steps; h-tile staged via LDS (is_init-masked); c in regs.
// gates = Gx[t] (precomputed, incl. biases) + h_eff @ W_hh^T.
// ---------------------------------------------------------------------------
__global__ __launch_bounds__(256, 1) void recur_kernel(
    const float* __restrict__ Whh,       // (2048,512) fp32
    const int* __restrict__ is_init,     // (NB,TT)
    const float* __restrict__ cx,        // (NB,TT,HH) fp32
    const ushort_t* __restrict__ gx_lo,  // (64,NB,2048) bf16
    const ushort_t* __restrict__ gx_hi,  // (64,NB,2048) bf16
    ushort_t* __restrict__ hp0,          // (NB,HH) bf16 ping (pre-inited h0)
    ushort_t* __restrict__ hp1,          // (NB,HH) bf16 pong
    ushort_t* __restrict__ hsb,          // (NB,TT,HH) bf16 all h_t
    float* __restrict__ c_out,           // (NB,HH) fp32 final c
    unsigned* __restrict__ bar_cnt, unsigned* __restrict__ bar_sns)
{
    __shared__ ushort_t hA[16 * 520];        // pad: row stride 520 shorts
    __shared__ float gbuf[4][16][32];

    const int tid  = threadIdx.x;
    const int gate = tid >> 6;
    const int lane = tid & 63;
    const int q    = lane >> 4;
    const int l15  = lane & 15;
    const int bm   = blockIdx.x >> 4;     // 0..15
    const int h0   = (blockIdx.x & 15) * 32;
    unsigned my_sense = 0u;

    // ---- preload W_hh B-fragments (fp32 -> bf16) into registers: 128 VGPRs
    short8 bfrag[2][16];
#pragma unroll
    for (int j = 0; j < 2; ++j) {
        const float* wr = Whh + (size_t)(gate * 512 + h0 + j * 16 + l15) * 512;
#pragma unroll
        for (int kk = 0; kk < 16; ++kk) {
            const float* p = wr + kk * 32 + q * 8;
            float4 f0 = *(const float4*)p;
            float4 f1 = *(const float4*)(p + 4);
            short8 v;
            v[0] = (short)f2bf(f0.x); v[1] = (short)f2bf(f0.y);
            v[2] = (short)f2bf(f0.z); v[3] = (short)f2bf(f0.w);
            v[4] = (short)f2bf(f1.x); v[5] = (short)f2bf(f1.y);
            v[6] = (short)f2bf(f1.z); v[7] = (short)f2bf(f1.w);
            bfrag[j][kk] = v;
        }
    }

    // ---- c-state in registers: thread owns elems (n_c, h0+hc), (n_c, h0+hc+1)
    const int m_c = tid >> 4;             // 0..15
    const int hc  = (tid * 2) & 31;       // 0,2,..,30
    const int n_c = bm * 16 + m_c;
    float2 c2 = *(const float2*)(cx + (size_t)n_c * TT * HH + h0 + hc);

    for (int t = 0; t < TT; ++t) {
        const ushort_t* cur = (t & 1) ? hp1 : hp0;
        ushort_t*       nxt = (t & 1) ? hp0 : hp1;

        // prefetch this step's Gx early (used only in pointwise phase)
        const ushort_t* gxp = ((t < 64) ? (gx_lo + (size_t)t * NB * 2048)
                                        : (gx_hi + (size_t)(t - 64) * NB * 2048))
                              + (size_t)n_c * 2048 + h0 + hc;
        ushort2 gxu[4];
#pragma unroll
        for (int g = 0; g < 4; ++g) gxu[g] = *(const ushort2*)(gxp + g * 512);

        // stage h-tile (16 x 512) to LDS, rows zeroed where is_init==1
#pragma unroll
        for (int i = 0; i < 4; ++i) {
            int idx = i * 256 + tid;
            int row = idx >> 6;
            int cc  = (idx & 63) * 8;
            ushort8 v = {0, 0, 0, 0, 0, 0, 0, 0};
            if (!is_init[(bm * 16 + row) * TT + t])
                v = *(const ushort8*)(cur + (size_t)(bm * 16 + row) * HH + cc);
            *(ushort8*)&hA[row * 520 + cc] = v;
        }
        __syncthreads();

        floatx4 a0 = {0.f, 0.f, 0.f, 0.f}, a1 = {0.f, 0.f, 0.f, 0.f};
#pragma unroll
        for (int kk = 0; kk < 16; ++kk) {
            short8 af = *(const short8*)&hA[l15 * 520 + kk * 32 + q * 8];
            a0 = __builtin_amdgcn_mfma_f32_16x16x32_bf16(af, bfrag[0][kk], a0, 0, 0, 0);
            a1 = __builtin_amdgcn_mfma_f32_16x16x32_bf16(af, bfrag[1][kk], a1, 0, 0, 0);
        }
#pragma unroll
        for (int r = 0; r < 4; ++r) {
            gbuf[gate][q * 4 + r][l15]      = a0[r];
            gbuf[gate][q * 4 + r][16 + l15] = a1[r];
        }
        __syncthreads();

        // pointwise cell update for this thread's 2 elements
        float g4[4][2];
#pragma unroll
        for (int g = 0; g < 4; ++g) {
            g4[g][0] = bf2f(gxu[g].x) + gbuf[g][m_c][hc];
            g4[g][1] = bf2f(gxu[g].y) + gbuf[g][m_c][hc + 1];
        }
        const int rst = is_init[n_c * TT + t];
        float cp0 = rst ? 0.f : c2.x;
        float cp1 = rst ? 0.f : c2.y;
        float cn0 = sigmoid_(g4[1][0]) * cp0 + sigmoid_(g4[0][0]) * tanh_fast(g4[2][0]);
        float cn1 = sigmoid_(g4[1][1]) * cp1 + sigmoid_(g4[0][1]) * tanh_fast(g4[2][1]);
        float hn0 = sigmoid_(g4[3][0]) * tanh_fast(cn0);
        float hn1 = sigmoid_(g4[3][1]) * tanh_fast(cn1);
        c2.x = cn0; c2.y = cn1;

        ushort2 hb;
        hb.x = f2bf(hn0); hb.y = f2bf(hn1);
        *(ushort2*)(nxt + (size_t)n_c * HH + h0 + hc) = hb;
        *(ushort2*)(hsb + ((size_t)n_c * TT + t) * HH + h0 + hc) = hb;

        if (t != TT - 1) grid_barrier(bar_cnt, bar_sns, my_sense);
    }

    // final c (final h already in hp0: t=127 wrote nxt=hp0)
    *(float2*)(c_out + (size_t)n_c * HH + h0 + hc) = c2;
}

// ---------------------------------------------------------------------------
// Broadcast h_T / c_T to (NB,TT,HH) fp32.
// ---------------------------------------------------------------------------
__global__ __launch_bounds__(256) void broadcast_kernel(
    const ushort_t* __restrict__ hT,   // (NB,HH) bf16
    const float* __restrict__ cT,      // (NB,HH) fp32
    float* __restrict__ h_rep, float* __restrict__ c_rep)
{
    size_t idx  = (size_t)blockIdx.x * 256 + threadIdx.x;
    size_t flat = idx * 8;
    int m = (int)(flat >> 16);
    int h = (int)(flat & 511);

    const ushort_t* hp = hT + (size_t)m * HH + h;
    const float*    cp = cT + (size_t)m * HH + h;

    float4 h0v, h1v, c0v, c1v;
    h0v.x = bf2f(hp[0]); h0v.y = bf2f(hp[1]); h0v.z = bf2f(hp[2]); h0v.w = bf2f(hp[3]);
    h1v.x = bf2f(hp[4]); h1v.y = bf2f(hp[5]); h1v.z = bf2f(hp[6]); h1v.w = bf2f(hp[7]);
    c0v.x = cp[0]; c0v.y = cp[1]; c0v.z = cp[2]; c0v.w = cp[3];
    c1v.x = cp[4]; c1v.y = cp[5]; c1v.z = cp[6]; c1v.w = cp[7];

    *(float4*)(h_rep + flat)     = h0v;
    *(float4*)(h_rep + flat + 4) = h1v;
    *(float4*)(c_rep + flat)     = c0v;
    *(float4*)(c_rep + flat + 4) = c1v;
}

// ---------------------------------------------------------------------------
extern "C" void kernel_launch(void* const* d_in, const int* in_sizes, int n_in,
                              void* d_out, int out_size, void* d_ws, size_t ws_size,
                              hipStream_t stream) {
    const float* x      = (const float*)d_in[0];
    const int*   isini  = (const int*)d_in[1];
    const float* hx     = (const float*)d_in[2];
    const float* cx     = (const float*)d_in[3];
    const float* W_ih   = (const float*)d_in[4];
    const float* W_hh   = (const float*)d_in[5];
    const float* b_ih   = (const float*)d_in[6];
    const float* b_hh   = (const float*)d_in[7];
    const float* W_out  = (const float*)d_in[8];
    const float* b_out  = (const float*)d_in[9];

    float* out   = (float*)d_out;
    float* h_rep = out + (size_t)NTH;
    float* c_rep = out + (size_t)2 * NTH;

    // Staging in dead d_out regions (stream-ordered overwrites):
    //  Gx (t<64)  -> out0 region  (consumed by recur; overwritten by outproj)
    //  Gx (t>=64) -> c_rep region (consumed by recur; overwritten by broadcast)
    //  hsb        -> h_rep lower half (written by recur; consumed by outproj)
    //  xb         -> h_rep upper half (consumed by Gx GEMM)
    ushort_t* gx_lo = (ushort_t*)out;
    ushort_t* gx_hi = (ushort_t*)c_rep;
    ushort_t* hsb   = (ushort_t*)h_rep;
    ushort_t* xb    = (ushort_t*)h_rep + (size_t)NTH;

    // workspace (~3.6 MiB)
    char* wsb = (char*)d_ws;
    ushort_t* hp0     = (ushort_t*)wsb;                                   // 256 KiB
    ushort_t* hp1     = (ushort_t*)(wsb + (size_t)NB * HH * 2);           // 256 KiB
    float*    c_state = (float*)(wsb + (size_t)2 * NB * HH * 2);          // 512 KiB
    float*    b_comb  = (float*)(wsb + (size_t)2 * NB * HH * 2
                                     + (size_t)NB * HH * 4);              // 8 KiB
    ushort_t* woutb   = (ushort_t*)(wsb + (size_t)2 * NB * HH * 2
                                        + (size_t)NB * HH * 4 + 4 * HH * 4); // 512 KiB
    ushort_t* wihb    = woutb + (size_t)HH * HH;                          // 2 MiB
    unsigned* bar_cnt = (unsigned*)(wihb + (size_t)4 * HH * II);
    unsigned* bar_sns = bar_cnt + 64;    // separate cacheline

    // --- prep ---
    cvt_bf16_kernel<<<NTH / 8 / 256, 256, 0, stream>>>(x, xb, NTH / 8);
    cvt_bf16_kernel<<<4 * HH * II / 8 / 256, 256, 0, stream>>>(W_ih, wihb, 4 * HH * II / 8);
    cvt_bf16_kernel<<<HH * HH / 8 / 256, 256, 0, stream>>>(W_out, woutb, HH * HH / 8);
    init_kernel<<<NB * HH / 256, 256, 0, stream>>>(hx, b_ih, b_hh, hp0, b_comb,
                                                   bar_cnt, bar_sns);

    // --- Gx = x @ W_ih^T + (b_ih + b_hh), bf16, layout (t, n, 2048) ---
    gemm_kernel<0><<<16 * 256, 256, 0, stream>>>(xb, wihb, b_comb, gx_lo, gx_hi, nullptr);

    // --- persistent recurrence, normal launch + manual grid barrier ---
    recur_kernel<<<RBLK, 256, 0, stream>>>(W_hh, isini, cx, gx_lo, gx_hi,
                                           hp0, hp1, hsb, c_state,
                                           bar_cnt, bar_sns);

    // --- out0 = mish(hs @ W_out^T + b_out) ---
    gemm_kernel<1><<<4 * 256, 256, 0, stream>>>(hsb, woutb, b_out, nullptr, nullptr, out);

    // --- h_rep / c_rep broadcasts (final h in hp0) ---
    broadcast_kernel<<<NTH / 8 / 256, 256, 0, stream>>>(hp0, c_state, h_rep, c_rep);
}